// Round 3
// baseline (560.892 us; speedup 1.0000x reference)
//
#include <hip/hip_runtime.h>
#include <stdint.h>

#define NA 6144
#define NC 80
#define NW 96          // 6144/64 mask words per row
#define NB 256         // blocks (<= 256 CUs -> co-resident)
#define NT 256         // threads per block

typedef unsigned long long u64;

// ---------------- static device scratch ----------------
__device__ u64    g_mask[(size_t)NA * NW];   // IoU>0.5 bitmask rows (sorted space)
__device__ float4 g_boxes[NA];
__device__ float4 g_sbox[NA];
__device__ __align__(16) float g_key[NA];    // score if valid else -1
__device__ int    g_sAnchor[NA];
__device__ int    g_sFi[NA];
__device__ int    g_keptPos[NA];

struct Ctl { int bar[8]; int F; int K; int np; float loss; };
__device__ Ctl g_ctl;                         // zeroed via hipMemsetAsync each launch

__device__ __forceinline__ u64 shfl64(u64 v, int l) {
    int lo = __shfl((int)(v & 0xffffffffull), l, 64);
    int hi = __shfl((int)(v >> 32), l, 64);
    return ((u64)(unsigned)hi << 32) | (unsigned)lo;
}

// software grid barrier: device-scope atomics, counters pre-zeroed each launch
__device__ __forceinline__ void gbar(int id) {
    __syncthreads();
    if (threadIdx.x == 0) {
        __threadfence();
        atomicAdd(&g_ctl.bar[id], 1);
        while (__hip_atomic_load(&g_ctl.bar[id], __ATOMIC_ACQUIRE,
                                 __HIP_MEMORY_SCOPE_AGENT) < NB)
            __builtin_amdgcn_s_sleep(1);
        __threadfence();
    }
    __syncthreads();
}

__global__ void __launch_bounds__(NT, 1)
k_fused(const float* __restrict__ loc, const float* __restrict__ conf,
        const float* __restrict__ tb, float* __restrict__ out) {
    const int tid  = blockIdx.x * NT + threadIdx.x;
    const int lane = threadIdx.x & 63;

    // ================= P1: filter + box build + F count =================
    if (tid < NA * 4) {                         // blocks 0..95 exactly
        int a = tid >> 2, q = tid & 3;
        const float4* cp4 = (const float4*)(conf + (size_t)a * NC) + q * 5;
        float4 v0 = cp4[0];
        float m = fmaxf(fmaxf(v0.x, v0.y), fmaxf(v0.z, v0.w));
        #pragma unroll
        for (int c = 1; c < 5; ++c) {
            float4 v = cp4[c];
            m = fmaxf(m, fmaxf(fmaxf(v.x, v.y), fmaxf(v.z, v.w)));
        }
        m = fmaxf(m, __shfl_xor(m, 1, 64));
        m = fmaxf(m, __shfl_xor(m, 2, 64));
        bool valid = m > 0.5f;
        if (q == 0) {
            g_key[a] = valid ? v0.x : -1.0f;    // score = conf[a][0]
            float2 p = ((const float2*)loc)[a];
            float4 b;
            b.x = __fmul_rn(tb[0], p.x);
            b.y = __fmul_rn(tb[1], p.y);
            b.z = __fmul_rn(tb[2], p.x);
            b.w = __fmul_rn(tb[3], p.y);
            g_boxes[a] = b;
        }
        u64 bal = __ballot(valid && q == 0);
        if (lane == 0) atomicAdd(&g_ctl.F, (int)__popcll(bal));
    }

    gbar(0);

    // ================= P2: stable-desc rank + scatter =================
    {
        int a = tid >> 3, s = tid & 7;          // 8 threads per anchor
        if (a < NA) {
            float ki = g_key[a];
            const float4* k4 = (const float4*)g_key;
            int r = 0, f = 0;
            for (int jj = 0; jj < 192; ++jj) {
                int i4 = jj * 8 + s;
                float4 kj = k4[i4];
                int j0 = i4 * 4;
                r += (kj.x > ki) || (kj.x == ki && (j0 + 0) < a);
                r += (kj.y > ki) || (kj.y == ki && (j0 + 1) < a);
                r += (kj.z > ki) || (kj.z == ki && (j0 + 2) < a);
                r += (kj.w > ki) || (kj.w == ki && (j0 + 3) < a);
                f += ((j0 + 0) < a) && (kj.x >= 0.0f);
                f += ((j0 + 1) < a) && (kj.y >= 0.0f);
                f += ((j0 + 2) < a) && (kj.z >= 0.0f);
                f += ((j0 + 3) < a) && (kj.w >= 0.0f);
            }
            r += __shfl_xor(r, 1, 64); r += __shfl_xor(r, 2, 64); r += __shfl_xor(r, 4, 64);
            f += __shfl_xor(f, 1, 64); f += __shfl_xor(f, 2, 64); f += __shfl_xor(f, 4, 64);
            if (s == 0 && ki >= 0.0f) {
                g_sAnchor[r] = a;
                g_sFi[r] = f;
                g_sbox[r] = g_boxes[a];
            }
        }
    }

    gbar(1);

    // ================= P3: IoU>0.5 bitmask (upper triangle) =================
    {
        int gw = tid >> 6;                      // 1024 waves
        for (int row = gw; row < NA; row += (NB * NT) / 64) {
            float4 bi = g_sbox[row];
            float areai = __fmul_rn(bi.z - bi.x, bi.w - bi.y);
            u64* rp = g_mask + (size_t)row * NW;
            for (int w = row >> 6; w < NW; ++w) {
                float4 bj = g_sbox[w * 64 + lane];
                float areaj = __fmul_rn(bj.z - bj.x, bj.w - bj.y);
                float lx = fmaxf(bi.x, bj.x), ly = fmaxf(bi.y, bj.y);
                float rx = fminf(bi.z, bj.z), ry = fminf(bi.w, bj.w);
                float iw = fmaxf(rx - lx, 0.0f), ih = fmaxf(ry - ly, 0.0f);
                float inter = __fmul_rn(iw, ih);
                float denom = __fsub_rn(__fadd_rn(areai, areaj), inter);
                float iou = __fdiv_rn(inter, denom);
                u64 bits = __ballot(iou > 0.5f);
                if (lane == 0) rp[w] = bits;
            }
        }
    }

    gbar(2);

    // ================= P4: greedy NMS scan (block 0, wave 0) =================
    if (blockIdx.x == 0 && threadIdx.x < 64) {
        int F = g_ctl.F;
        auto initw = [&](int w) -> u64 {
            long long lo = (long long)w * 64, hi = lo + 64;
            if (F <= lo) return ~0ull;
            if (F >= hi) return 0ull;
            return (~0ull) << (F - lo);
        };
        u64 remv0 = initw(lane);                            // word lane
        u64 remv1 = (lane < 32) ? initw(64 + lane) : ~0ull; // word 64+lane
        u64 kept0 = 0, kept1 = 0;

        auto getRemv = [&](int w) -> u64 {
            return (w < 64) ? shfl64(remv0, w) : shfl64(remv1, w - 64);
        };

        int scanW = 0;
        u64 scanRem = ~getRemv(0);

        int posA[8], posB[8], posC[8];
        u64 loA[8], hiA[8], loB[8], hiB[8], loC[8], hiC[8];

        // fill: enqueue next 8 candidate positions (wave-uniform scanner) and
        // issue their row loads branchlessly (dummy row 0 for empty slots).
        auto fill = [&](int* pos, u64* lo, u64* hi) -> int {
            scanRem &= ~getRemv(scanW);     // drop newly suppressed bits
            int n = 0;
            #pragma unroll
            for (int q = 0; q < 8; ++q) {
                while (scanRem == 0 && scanW < NW - 1) { ++scanW; scanRem = ~getRemv(scanW); }
                int p = -1;
                if (scanRem) {
                    int b = __builtin_ctzll(scanRem);
                    scanRem &= scanRem - 1;
                    p = (scanW << 6) | b;
                    ++n;
                }
                pos[q] = p;
            }
            #pragma unroll
            for (int q = 0; q < 8; ++q) {
                const u64* row = g_mask + (size_t)(pos[q] < 0 ? 0 : pos[q]) * NW;
                lo[q] = row[lane];
                hi[q] = row[64 + (lane & 31)];   // lanes>=32 duplicate (harmless)
            }
            return n;
        };

        auto resolve = [&](const int* pos, const u64* lo, const u64* hi) {
            #pragma unroll
            for (int q = 0; q < 8; ++q) {
                int p = pos[q];
                if (p < 0) break;               // wave-uniform
                int wq = p >> 6, bq = p & 63;
                bool ownerbit;
                if (wq < 64) ownerbit = (lane == wq) && ((remv0 >> bq) & 1ull);
                else         ownerbit = (lane == wq - 64) && ((remv1 >> bq) & 1ull);
                bool suppressed = __ballot(ownerbit) != 0ull;
                if (!suppressed) {
                    remv0 |= lo[q];
                    remv1 |= hi[q];
                    if (wq < 64) { if (lane == wq) kept0 |= 1ull << bq; }
                    else         { if (lane == wq - 64) kept1 |= 1ull << bq; }
                }
            }
        };

        int nA = fill(posA, loA, hiA);
        if (nA) {
            int nB = fill(posB, loB, hiB);
            int nC;
            for (;;) {
                nC = fill(posC, loC, hiC);
                resolve(posA, loA, hiA);        // compiler waits vmcnt for A only
                if (nB == 0) break;
                nA = fill(posA, loA, hiA);
                resolve(posB, loB, hiB);
                if (nC == 0) break;
                nB = fill(posB, loB, hiB);
                resolve(posC, loC, hiC);
                if (nA == 0) break;
            }
        }

        // compact kept list (ascending sorted positions)
        int c0 = __popcll(kept0);
        int c1 = (lane < 32) ? __popcll(kept1) : 0;
        int x0 = c0, x1 = c1;
        for (int ofs = 1; ofs < 64; ofs <<= 1) {
            int y0 = __shfl_up(x0, ofs, 64);
            int y1 = __shfl_up(x1, ofs, 64);
            if (lane >= ofs) { x0 += y0; x1 += y1; }
        }
        int t0 = __shfl(x0, 63, 64);
        int t1 = __shfl(x1, 63, 64);
        int off = x0 - c0;
        u64 wd = kept0;
        while (wd) { int b = __builtin_ctzll(wd); g_keptPos[off++] = lane * 64 + b; wd &= wd - 1; }
        off = t0 + (x1 - c1);
        wd = kept1;
        while (wd) { int b = __builtin_ctzll(wd); g_keptPos[off++] = (64 + lane) * 64 + b; wd &= wd - 1; }
        if (lane == 0) g_ctl.K = t0 + t1;
    }

    gbar(3);

    // ================= P5: per-class top-1 + smooth-L1 + num_pos =================
    {
        int K = g_ctl.K;
        if (blockIdx.x < NC && (threadIdx.x >> 6) == 0) {
            int c = blockIdx.x;
            float bv = -3.402823466e+38f;
            int bk = 0x7fffffff;
            for (int k = lane; k < K; k += 64) {
                int p = g_keptPos[k];
                int a = g_sAnchor[p];
                float v = conf[(size_t)a * NC + c];
                if (v > bv || (v == bv && k < bk)) { bv = v; bk = k; }
            }
            for (int ofs = 32; ofs > 0; ofs >>= 1) {
                float ov = __shfl_down(bv, ofs, 64);
                int ok = __shfl_down(bk, ofs, 64);
                if (ov > bv || (ov == bv && ok < bk)) { bv = ov; bk = ok; }
            }
            if (lane == 0 && K > 0) {
                float4 b = g_sbox[g_keptPos[bk]];
                float t0 = tb[0], t1 = tb[1], t2 = tb[2], t3 = tb[3];
                float l = 0.0f, d;
                d = fabsf(b.x - t0); l += (d < 1.0f) ? 0.5f * d * d : d - 0.5f;
                d = fabsf(b.y - t1); l += (d < 1.0f) ? 0.5f * d * d : d - 0.5f;
                d = fabsf(b.z - t2); l += (d < 1.0f) ? 0.5f * d * d : d - 0.5f;
                d = fabsf(b.w - t3); l += (d < 1.0f) ? 0.5f * d * d : d - 0.5f;
                atomicAdd(&g_ctl.loss, l);
            }
        }
        if (blockIdx.x == 0 && (threadIdx.x >> 6) == 1) {
            int np = 0;
            for (int k = lane; k < K; k += 64) np += g_sFi[g_keptPos[k]];
            for (int ofs = 32; ofs > 0; ofs >>= 1) np += __shfl_down(np, ofs, 64);
            if (lane == 0) g_ctl.np = np;
        }
    }

    gbar(4);

    // ================= P6: finalize =================
    if (blockIdx.x == 0 && threadIdx.x == 0) {
        out[0] = (g_ctl.F == 0 || g_ctl.K == 0) ? 0.001f
                                                : g_ctl.loss / (float)g_ctl.np;
    }
}

extern "C" void kernel_launch(void* const* d_in, const int* in_sizes, int n_in,
                              void* d_out, int out_size, void* d_ws, size_t ws_size,
                              hipStream_t stream) {
    const float* loc  = (const float*)d_in[0];   // (1, 6144, 2)  f32
    const float* conf = (const float*)d_in[1];   // (1, 6144, 80) f32
    const float* tb   = (const float*)d_in[2];   // (1, 1, 4)     f32
    float* out = (float*)d_out;

    void* ctl = nullptr;
    hipGetSymbolAddress(&ctl, HIP_SYMBOL(g_ctl));
    hipMemsetAsync(ctl, 0, sizeof(Ctl), stream);   // zero barriers/F/K/np/loss

    k_fused<<<NB, NT, 0, stream>>>(loc, conf, tb, out);
}

// Round 4
// 232.722 us; speedup vs baseline: 2.4101x; 2.4101x over previous
//
#include <hip/hip_runtime.h>
#include <stdint.h>

#define NA 6144
#define NC 80
#define NW 96          // mask words per row

typedef unsigned long long u64;

// ---------------- static device scratch (no zero-init required anywhere) ----------------
__device__ u64    g_mask[(size_t)NA * NW];   // IoU>0.5 bitmask rows (sorted space)
__device__ float4 g_boxes[NA];
__device__ float4 g_sbox[NA];
__device__ __align__(16) float g_key[NA];    // score if valid else -1
__device__ int    g_sAnchor[NA];
__device__ int    g_sFi[NA];

__device__ __forceinline__ u64 shfl64(u64 v, int l) {
    int lo = __shfl((int)(v & 0xffffffffull), l, 64);
    int hi = __shfl((int)(v >> 32), l, 64);
    return ((u64)(unsigned)hi << 32) | (unsigned)lo;
}

// ---------------- K1: filter + box build ----------------
__global__ void __launch_bounds__(256) k_prep(const float* __restrict__ loc,
                                              const float* __restrict__ conf,
                                              const float* __restrict__ tb) {
    int tid = blockIdx.x * 256 + threadIdx.x;   // grid 96 -> NA*4 threads
    int a = tid >> 2, q = tid & 3;
    const float4* cp4 = (const float4*)(conf + (size_t)a * NC) + q * 5;
    float4 v0 = cp4[0];
    float m = fmaxf(fmaxf(v0.x, v0.y), fmaxf(v0.z, v0.w));
    #pragma unroll
    for (int c = 1; c < 5; ++c) {
        float4 v = cp4[c];
        m = fmaxf(m, fmaxf(fmaxf(v.x, v.y), fmaxf(v.z, v.w)));
    }
    m = fmaxf(m, __shfl_xor(m, 1, 64));
    m = fmaxf(m, __shfl_xor(m, 2, 64));
    if (q == 0) {
        g_key[a] = (m > 0.5f) ? v0.x : -1.0f;   // score = conf[a][0]
        float2 p = ((const float2*)loc)[a];
        float4 b;
        b.x = __fmul_rn(tb[0], p.x);
        b.y = __fmul_rn(tb[1], p.y);
        b.z = __fmul_rn(tb[2], p.x);
        b.w = __fmul_rn(tb[3], p.y);
        g_boxes[a] = b;
    }
}

// ---------------- K2: stable-desc rank + scatter (no atomics, no partials) ----------------
__global__ void __launch_bounds__(256) k_rankscatter(void) {
    int tid = blockIdx.x * 256 + threadIdx.x;   // grid 192 -> NA*8 threads
    int a = tid >> 3, s = tid & 7;              // 8 threads per anchor
    float ki = g_key[a];
    const float4* k4 = (const float4*)g_key;
    int r = 0, f = 0;
    for (int jj = 0; jj < 192; ++jj) {
        int i4 = jj * 8 + s;
        float4 kj = k4[i4];
        int j0 = i4 * 4;
        r += (kj.x > ki) || (kj.x == ki && (j0 + 0) < a);
        r += (kj.y > ki) || (kj.y == ki && (j0 + 1) < a);
        r += (kj.z > ki) || (kj.z == ki && (j0 + 2) < a);
        r += (kj.w > ki) || (kj.w == ki && (j0 + 3) < a);
        f += ((j0 + 0) < a) && (kj.x >= 0.0f);
        f += ((j0 + 1) < a) && (kj.y >= 0.0f);
        f += ((j0 + 2) < a) && (kj.z >= 0.0f);
        f += ((j0 + 3) < a) && (kj.w >= 0.0f);
    }
    r += __shfl_xor(r, 1, 64); r += __shfl_xor(r, 2, 64); r += __shfl_xor(r, 4, 64);
    f += __shfl_xor(f, 1, 64); f += __shfl_xor(f, 2, 64); f += __shfl_xor(f, 4, 64);
    if (s == 0 && ki >= 0.0f) {
        g_sAnchor[r] = a;
        g_sFi[r] = f;
        g_sbox[r] = g_boxes[a];
    }
}

// ---------------- K3: IoU>0.5 bitmask (upper triangle; lower words stay garbage,
// harmless: scan only ever consumes words >= the candidate's own word) ----------------
__global__ void __launch_bounds__(256) k_mask(void) {
    int wave = (blockIdx.x * 256 + threadIdx.x) >> 6;   // 6144 waves, one row each
    int lane = threadIdx.x & 63;
    float4 bi = g_sbox[wave];
    float areai = __fmul_rn(bi.z - bi.x, bi.w - bi.y);
    u64* rp = g_mask + (size_t)wave * NW;
    for (int w = wave >> 6; w < NW; ++w) {
        float4 bj = g_sbox[w * 64 + lane];
        float areaj = __fmul_rn(bj.z - bj.x, bj.w - bj.y);
        float lx = fmaxf(bi.x, bj.x), ly = fmaxf(bi.y, bj.y);
        float rx = fminf(bi.z, bj.z), ry = fminf(bi.w, bj.w);
        float iw = fmaxf(rx - lx, 0.0f), ih = fmaxf(ry - ly, 0.0f);
        float inter = __fmul_rn(iw, ih);
        float denom = __fsub_rn(__fadd_rn(areai, areaj), inter);
        float iou = __fdiv_rn(inter, denom);
        u64 bits = __ballot(iou > 0.5f);
        if (lane == 0) rp[w] = bits;
    }
}

// ---------------- K4: scan (wave 0) + loss (4 waves) + finalize, one block ----------------
#define GETREMV(w) (((w) < 64) ? shfl64(remv0, (w)) : shfl64(remv1, (w) - 64))

#define FILL1(P, L, H) { \
    while (scanRem == 0 && scanW < NW - 1) { ++scanW; scanRem = ~GETREMV(scanW); } \
    if (scanRem) { int _b = __builtin_ctzll(scanRem); scanRem &= scanRem - 1; \
                   P = (scanW << 6) | _b; } \
    else P = -1; \
    { const u64* _row = g_mask + (size_t)(P < 0 ? 0 : P) * NW; \
      L = _row[lane]; H = _row[64 + (lane & 31)]; } }

#define RESOLVE1(P, L, H) { \
    if (P >= 0) { \
        int _w = P >> 6, _b = P & 63; \
        if (_w != rw) { rw = _w; rm = GETREMV(rw); } \
        if (!((rm >> _b) & 1ull)) { \
            u64 _rw2 = (rw < 64) ? shfl64(L, rw) : shfl64(H, rw - 64); \
            rm |= _rw2; \
            remv0 |= L; remv1 |= H; \
            if (_w < 64) { if (lane == _w) kept0 |= 1ull << _b; } \
            else         { if (lane == _w - 64) kept1 |= 1ull << _b; } \
        } \
    } }

#define REP16(M, X) M(X,0) M(X,1) M(X,2) M(X,3) M(X,4) M(X,5) M(X,6) M(X,7) \
                    M(X,8) M(X,9) M(X,10) M(X,11) M(X,12) M(X,13) M(X,14) M(X,15)
#define DECL_SLOT(X, N) int p##X##N; u64 l##X##N, h##X##N;
#define FILL_SLOT(X, N) FILL1(p##X##N, l##X##N, h##X##N)
#define RES_SLOT(X, N)  RESOLVE1(p##X##N, l##X##N, h##X##N)
#define DECL_BUF(X) REP16(DECL_SLOT, X)
#define FILL_BUF(X) { scanRem &= ~GETREMV(scanW); REP16(FILL_SLOT, X) }
#define RES_BUF(X)  { REP16(RES_SLOT, X) }

__global__ void __launch_bounds__(256, 1)
k_scanloss(const float* __restrict__ conf, const float* __restrict__ tb,
           float* __restrict__ out) {
    __shared__ int sKept[NA];
    __shared__ int sA[NA];
    __shared__ float sloss[NC];
    __shared__ int sK, sNp, sF;
    const int lane = threadIdx.x & 63;
    const int wv = threadIdx.x >> 6;

    if (wv == 0) {
        // ---- count F (valid anchors) ----
        const float4* k4 = (const float4*)g_key;
        int F = 0;
        #pragma unroll
        for (int j = 0; j < 24; ++j) {
            float4 kk = k4[j * 64 + lane];
            F += (kk.x >= 0.0f) + (kk.y >= 0.0f) + (kk.z >= 0.0f) + (kk.w >= 0.0f);
        }
        #pragma unroll
        for (int ofs = 1; ofs < 64; ofs <<= 1) F += __shfl_xor(F, ofs, 64);

        // ---- greedy NMS scan, triple-buffered 16-slot pipeline ----
        auto initw = [&](int w) -> u64 {
            long long lo = (long long)w * 64, hi = lo + 64;
            if (F <= lo) return ~0ull;
            if (F >= hi) return 0ull;
            return (~0ull) << (F - lo);
        };
        u64 remv0 = initw(lane);                            // word lane
        u64 remv1 = (lane < 32) ? initw(64 + lane) : ~0ull; // word 64+lane
        u64 kept0 = 0, kept1 = 0;
        int scanW = 0;
        u64 scanRem = ~GETREMV(0);
        int rw = -1; u64 rm = 0;

        DECL_BUF(A) DECL_BUF(B) DECL_BUF(C)
        int nA, nB, nC;
        FILL_BUF(A); nA = (pA0 >= 0);
        if (nA) {
            FILL_BUF(B); nB = (pB0 >= 0);
            for (;;) {
                FILL_BUF(C); nC = (pC0 >= 0);
                RES_BUF(A);
                if (!nB) break;
                FILL_BUF(A); nA = (pA0 >= 0);
                RES_BUF(B);
                if (!nC) break;
                FILL_BUF(B); nB = (pB0 >= 0);
                RES_BUF(C);
                if (!nA) break;
            }
        }

        // ---- compact kept list (ascending sorted positions) into LDS ----
        int c0 = __popcll(kept0);
        int c1 = (lane < 32) ? __popcll(kept1) : 0;
        int x0 = c0, x1 = c1;
        for (int ofs = 1; ofs < 64; ofs <<= 1) {
            int y0 = __shfl_up(x0, ofs, 64);
            int y1 = __shfl_up(x1, ofs, 64);
            if (lane >= ofs) { x0 += y0; x1 += y1; }
        }
        int t0 = __shfl(x0, 63, 64);
        int t1 = __shfl(x1, 63, 64);
        int off = x0 - c0;
        u64 wd = kept0;
        while (wd) { int b = __builtin_ctzll(wd); sKept[off++] = lane * 64 + b; wd &= wd - 1; }
        off = t0 + (x1 - c1);
        wd = kept1;
        while (wd) { int b = __builtin_ctzll(wd); sKept[off++] = (64 + lane) * 64 + b; wd &= wd - 1; }
        int K = t0 + t1;
        if (lane == 0) { sK = K; sF = F; }

        // ---- sA[k] = anchor id of k-th kept; np = sum of filtered indices ----
        int np = 0;
        for (int k = lane; k < K; k += 64) {
            int p = sKept[k];
            sA[k] = g_sAnchor[p];
            np += g_sFi[p];
        }
        for (int ofs = 32; ofs > 0; ofs >>= 1) np += __shfl_down(np, ofs, 64);
        if (lane == 0) sNp = np;
    }
    __syncthreads();

    // ---- per-class top-1 (ties -> first kept) + smooth-L1, 4 waves x 20 classes ----
    int K = sK;
    if (K > 0) {
        float t0 = tb[0], t1 = tb[1], t2 = tb[2], t3 = tb[3];
        for (int c = wv; c < NC; c += 4) {
            float bv = -3.402823466e+38f;
            int bk = 0x7fffffff;
            for (int k = lane; k < K; k += 64) {
                float v = conf[(size_t)sA[k] * NC + c];
                if (v > bv || (v == bv && k < bk)) { bv = v; bk = k; }
            }
            for (int ofs = 32; ofs > 0; ofs >>= 1) {
                float ov = __shfl_down(bv, ofs, 64);
                int ok = __shfl_down(bk, ofs, 64);
                if (ov > bv || (ov == bv && ok < bk)) { bv = ov; bk = ok; }
            }
            if (lane == 0) {
                float4 b = g_sbox[sKept[bk]];
                float l = 0.0f, d;
                d = fabsf(b.x - t0); l += (d < 1.0f) ? 0.5f * d * d : d - 0.5f;
                d = fabsf(b.y - t1); l += (d < 1.0f) ? 0.5f * d * d : d - 0.5f;
                d = fabsf(b.z - t2); l += (d < 1.0f) ? 0.5f * d * d : d - 0.5f;
                d = fabsf(b.w - t3); l += (d < 1.0f) ? 0.5f * d * d : d - 0.5f;
                sloss[c] = l;
            }
        }
    }
    __syncthreads();

    if (threadIdx.x == 0) {
        if (sF == 0 || K == 0) {
            out[0] = 0.001f;
        } else {
            float l = 0.0f;
            for (int c = 0; c < NC; ++c) l += sloss[c];
            out[0] = l / (float)sNp;
        }
    }
}

extern "C" void kernel_launch(void* const* d_in, const int* in_sizes, int n_in,
                              void* d_out, int out_size, void* d_ws, size_t ws_size,
                              hipStream_t stream) {
    const float* loc  = (const float*)d_in[0];   // (1, 6144, 2)  f32
    const float* conf = (const float*)d_in[1];   // (1, 6144, 80) f32
    const float* tb   = (const float*)d_in[2];   // (1, 1, 4)     f32
    float* out = (float*)d_out;

    k_prep<<<96, 256, 0, stream>>>(loc, conf, tb);
    k_rankscatter<<<192, 256, 0, stream>>>();
    k_mask<<<(NA * 64) / 256, 256, 0, stream>>>();
    k_scanloss<<<1, 256, 0, stream>>>(conf, tb, out);
}